// Round 1
// baseline (224.457 us; speedup 1.0000x reference)
//
#include <hip/hip_runtime.h>
#include <hip/hip_bf16.h>

#define SIZE 4096
#define NBLK (SIZE / 128)

typedef __bf16 bf16x8 __attribute__((ext_vector_type(8)));
typedef float f32x4 __attribute__((ext_vector_type(4)));

// ---------------------------------------------------------------------------
// async global->LDS copy, 16 bytes per lane. LDS dest is wave-uniform base +
// lane*16 (guide §5): our LDS layout is linear in exactly that order.
// ---------------------------------------------------------------------------
__device__ __forceinline__ void gload_lds16(const void* gsrc, void* ldst) {
  __builtin_amdgcn_global_load_lds(
      (const __attribute__((address_space(1))) unsigned int*)gsrc,
      (__attribute__((address_space(3))) unsigned int*)ldst,
      16, 0, 0);
}

// ---------------------------------------------------------------------------
// Kernel 1: build L (bf16) from unconstrained params.
// One 256-thread block per row. Block-wide prefix product over v = 1 - tanh^2.
// L[i][j] = tanh(p_ij) * sqrt(prod_{k<j} v_ik),  L[i][i] = sqrt(prod_{k<i}),
// upper triangle = 0. fp32 throughout (matches reference underflow behavior).
// ---------------------------------------------------------------------------
__global__ __launch_bounds__(256) void build_L(const float* __restrict__ p,
                                               __bf16* __restrict__ Lb) {
  const int row = blockIdx.x;
  const int tid = threadIdx.x;
  const int lane = tid & 63;
  const int wid = tid >> 6;
  const long base = (long)row * (row - 1) / 2;

  __shared__ float wtot[4];
  float carry = 1.0f;

  for (int j0 = 0; j0 < SIZE; j0 += 256) {
    if (j0 > row) {  // block-uniform fast path: rest of row is zero
      Lb[(size_t)row * SIZE + j0 + tid] = (__bf16)0.0f;
      continue;
    }
    const int j = j0 + tid;
    float t, v;
    if (j < row) {
      t = tanhf(p[base + j]);
      v = 1.0f - t * t;
    } else {
      t = (j == row) ? 1.0f : 0.0f;  // diag gets z=1, upper gets 0
      v = 1.0f;
    }
    // wave-level inclusive scan (product)
    float incl = v;
#pragma unroll
    for (int off = 1; off < 64; off <<= 1) {
      float o = __shfl_up(incl, off, 64);
      if (lane >= off) incl *= o;
    }
    if (lane == 63) wtot[wid] = incl;
    __syncthreads();
    float pre = carry;
    for (int w = 0; w < wid; ++w) pre *= wtot[w];
    float excl = __shfl_up(incl, 1, 64);
    if (lane == 0) excl = 1.0f;
    const float s = pre * excl;  // exclusive prefix product up to j
    Lb[(size_t)row * SIZE + j] = (__bf16)(t * sqrtf(s));
    const float tot = wtot[0] * wtot[1] * wtot[2] * wtot[3];
    __syncthreads();  // wtot consumed before next chunk overwrites it
    carry *= tot;
  }
}

// ---------------------------------------------------------------------------
// Kernel 2: C = L * L^T  (bf16 inputs, fp32 accumulate/output).
// m97 structure: 128x128 tile, BK=32, 4 waves (2x2), 4x4 frags of
// mfma_f32_16x16x32_bf16 per wave, global_load_lds(16B) staging, 2 barriers.
// "B^T" operand is just L again (C[i][j] = sum_k L[i][k]*L[j][k]).
// ---------------------------------------------------------------------------
__global__ __launch_bounds__(256) void syrk_bf16(const __bf16* __restrict__ Lb,
                                                 float* __restrict__ C) {
  const int bid = blockIdx.x;
  const int bi = bid >> 5;   // 0..31 row block
  const int bj = bid & 31;   // 0..31 col block

  const int tid = threadIdx.x;
  const int lane = tid & 63;
  const int wid = tid >> 6;
  const int wr = wid >> 1;   // wave row 0..1
  const int wc = wid & 1;    // wave col 0..1

  __shared__ __bf16 As[128 * 32];  // [row][k], 64B rows
  __shared__ __bf16 Bs[128 * 32];  // [col][k]

  const int r16 = lane & 15;   // fragment row/col index
  const int kg = lane >> 4;    // k-group 0..3 (8 contiguous bf16 each)
  const int lrow = lane >> 2;  // staging: row within 16-row segment
  const int lcol = lane & 3;   // staging: 16B chunk within 64B row

  const int rowA0 = bi * 128;
  const int rowB0 = bj * 128;

  f32x4 acc[4][4] = {};

  for (int kt = 0; kt < SIZE / 32; ++kt) {
    const int k0 = kt * 32;
    __syncthreads();  // previous tile fully consumed
#pragma unroll
    for (int q = 0; q < 2; ++q) {
      const int seg = wid * 2 + q;          // 0..7, wave-uniform
      const int r = seg * 16 + lrow;        // 0..127
      gload_lds16(Lb + (size_t)(rowA0 + r) * SIZE + k0 + lcol * 8,
                  &As[seg * 512]);
      gload_lds16(Lb + (size_t)(rowB0 + r) * SIZE + k0 + lcol * 8,
                  &Bs[seg * 512]);
    }
    __syncthreads();  // drains vmcnt: tile ready

    bf16x8 af[4], bf[4];
#pragma unroll
    for (int m = 0; m < 4; ++m)
      af[m] = *reinterpret_cast<const bf16x8*>(
          &As[(wr * 64 + m * 16 + r16) * 32 + kg * 8]);
#pragma unroll
    for (int n = 0; n < 4; ++n)
      bf[n] = *reinterpret_cast<const bf16x8*>(
          &Bs[(wc * 64 + n * 16 + r16) * 32 + kg * 8]);
#pragma unroll
    for (int m = 0; m < 4; ++m)
#pragma unroll
      for (int n = 0; n < 4; ++n)
        acc[m][n] =
            __builtin_amdgcn_mfma_f32_16x16x32_bf16(af[m], bf[n], acc[m][n], 0, 0, 0);
  }

  // C/D layout (m89-verified): col = lane&15, row = (lane>>4)*4 + reg
  float* Cp = C + (size_t)(rowA0 + wr * 64) * SIZE + rowB0 + wc * 64;
#pragma unroll
  for (int m = 0; m < 4; ++m)
#pragma unroll
    for (int n = 0; n < 4; ++n)
#pragma unroll
      for (int j = 0; j < 4; ++j)
        Cp[(size_t)(m * 16 + kg * 4 + j) * SIZE + n * 16 + r16] = acc[m][n][j];
}

// ---------------------------------------------------------------------------
extern "C" void kernel_launch(void* const* d_in, const int* in_sizes, int n_in,
                              void* d_out, int out_size, void* d_ws, size_t ws_size,
                              hipStream_t stream) {
  const float* p = (const float*)d_in[0];
  float* C = (float*)d_out;
  __bf16* Lb = (__bf16*)d_ws;  // 4096*4096*2 = 32 MB scratch

  build_L<<<SIZE, 256, 0, stream>>>(p, Lb);
  syrk_bf16<<<NBLK * NBLK, 256, 0, stream>>>(Lb, C);
}

// Round 2
// 147.416 us; speedup vs baseline: 1.5226x; 1.5226x over previous
//
#include <hip/hip_runtime.h>
#include <hip/hip_bf16.h>

#define SIZE 4096
#define NBLK (SIZE / 128)
#define NTRI (NBLK * (NBLK + 1) / 2)  // 528 lower-triangular blocks

typedef __bf16 bf16x8 __attribute__((ext_vector_type(8)));
typedef float f32x4 __attribute__((ext_vector_type(4)));

// ---------------------------------------------------------------------------
// async global->LDS copy, 16 bytes per lane. LDS dest is wave-uniform base +
// lane*16 (guide §5): our LDS layout is linear in exactly that order.
// ---------------------------------------------------------------------------
__device__ __forceinline__ void gload_lds16(const void* gsrc, void* ldst) {
  __builtin_amdgcn_global_load_lds(
      (const __attribute__((address_space(1))) unsigned int*)gsrc,
      (__attribute__((address_space(3))) unsigned int*)ldst,
      16, 0, 0);
}

// ---------------------------------------------------------------------------
// Kernel 1: build L (bf16) from unconstrained params.
// One 256-thread block per row. Block-wide prefix product over v = 1 - tanh^2.
// ---------------------------------------------------------------------------
__global__ __launch_bounds__(256) void build_L(const float* __restrict__ p,
                                               __bf16* __restrict__ Lb) {
  const int row = blockIdx.x;
  const int tid = threadIdx.x;
  const int lane = tid & 63;
  const int wid = tid >> 6;
  const long base = (long)row * (row - 1) / 2;

  __shared__ float wtot[4];
  float carry = 1.0f;

  for (int j0 = 0; j0 < SIZE; j0 += 256) {
    if (j0 > row) {  // block-uniform fast path: rest of row is zero
      Lb[(size_t)row * SIZE + j0 + tid] = (__bf16)0.0f;
      continue;
    }
    const int j = j0 + tid;
    float t, v;
    if (j < row) {
      t = tanhf(p[base + j]);
      v = 1.0f - t * t;
    } else {
      t = (j == row) ? 1.0f : 0.0f;  // diag gets z=1, upper gets 0
      v = 1.0f;
    }
    // wave-level inclusive scan (product)
    float incl = v;
#pragma unroll
    for (int off = 1; off < 64; off <<= 1) {
      float o = __shfl_up(incl, off, 64);
      if (lane >= off) incl *= o;
    }
    if (lane == 63) wtot[wid] = incl;
    __syncthreads();
    float pre = carry;
    for (int w = 0; w < wid; ++w) pre *= wtot[w];
    float excl = __shfl_up(incl, 1, 64);
    if (lane == 0) excl = 1.0f;
    const float s = pre * excl;  // exclusive prefix product up to j
    Lb[(size_t)row * SIZE + j] = (__bf16)(t * sqrtf(s));
    const float tot = wtot[0] * wtot[1] * wtot[2] * wtot[3];
    __syncthreads();  // wtot consumed before next chunk overwrites it
    carry *= tot;
  }
}

// ---------------------------------------------------------------------------
// Kernel 2: C = L * L^T, symmetric — compute lower-tri blocks only, mirror.
// m97 structure: 128x128 tile, BK=32, 4 waves (2x2), 4x4 frags of
// mfma_f32_16x16x32_bf16 per wave, global_load_lds(16B) staging, 2 barriers.
// ---------------------------------------------------------------------------
__global__ __launch_bounds__(256) void syrk_bf16(const __bf16* __restrict__ Lb,
                                                 float* __restrict__ C) {
  // bid -> (bi, bj) with bi >= bj over the 528 lower-tri blocks
  const int bid = blockIdx.x;
  int bi = (int)((sqrtf(8.0f * bid + 1.0f) - 1.0f) * 0.5f);
  while ((bi + 1) * (bi + 2) / 2 <= bid) ++bi;  // float-rounding fixup
  while (bi * (bi + 1) / 2 > bid) --bi;
  const int bj = bid - bi * (bi + 1) / 2;

  const int tid = threadIdx.x;
  const int lane = tid & 63;
  const int wid = tid >> 6;
  const int wr = wid >> 1;   // wave row 0..1
  const int wc = wid & 1;    // wave col 0..1

  __shared__ __bf16 As[128 * 32];  // [row][k], 64B rows
  __shared__ __bf16 Bs[128 * 32];  // [col][k]

  const int r16 = lane & 15;   // fragment row/col index
  const int kg = lane >> 4;    // k-group 0..3 (8 contiguous bf16 each)
  const int lrow = lane >> 2;  // staging: row within 16-row segment
  const int lcol = lane & 3;   // staging: 16B chunk within 64B row

  const int rowA0 = bi * 128;
  const int rowB0 = bj * 128;

  f32x4 acc[4][4] = {};

  for (int kt = 0; kt < SIZE / 32; ++kt) {
    const int k0 = kt * 32;
    __syncthreads();  // previous tile fully consumed
#pragma unroll
    for (int q = 0; q < 2; ++q) {
      const int seg = wid * 2 + q;          // 0..7, wave-uniform
      const int r = seg * 16 + lrow;        // 0..127
      gload_lds16(Lb + (size_t)(rowA0 + r) * SIZE + k0 + lcol * 8,
                  &As[seg * 512]);
      gload_lds16(Lb + (size_t)(rowB0 + r) * SIZE + k0 + lcol * 8,
                  &Bs[seg * 512]);
    }
    __syncthreads();  // drains vmcnt: tile ready

    bf16x8 af[4], bf[4];
#pragma unroll
    for (int m = 0; m < 4; ++m)
      af[m] = *reinterpret_cast<const bf16x8*>(
          &As[(wr * 64 + m * 16 + r16) * 32 + kg * 8]);
#pragma unroll
    for (int n = 0; n < 4; ++n)
      bf[n] = *reinterpret_cast<const bf16x8*>(
          &Bs[(wc * 64 + n * 16 + r16) * 32 + kg * 8]);
#pragma unroll
    for (int m = 0; m < 4; ++m)
#pragma unroll
      for (int n = 0; n < 4; ++n)
        acc[m][n] =
            __builtin_amdgcn_mfma_f32_16x16x32_bf16(af[m], bf[n], acc[m][n], 0, 0, 0);
  }

  // C/D layout (m89-verified): col = lane&15, row = (lane>>4)*4 + reg
  // Direct block (bi,bj): element acc[m][n][j] -> (m*16+kg*4+j, n*16+r16)
  float* Cp = C + (size_t)(rowA0 + wr * 64) * SIZE + rowB0 + wc * 64;
#pragma unroll
  for (int m = 0; m < 4; ++m)
#pragma unroll
    for (int n = 0; n < 4; ++n)
#pragma unroll
      for (int j = 0; j < 4; ++j)
        Cp[(size_t)(m * 16 + kg * 4 + j) * SIZE + n * 16 + r16] = acc[m][n][j];

  // Mirror block (bj,bi): transposed -> row n*16+r16, cols m*16+kg*4 .. +3,
  // j consecutive in memory => one float4 store per fragment.
  if (bi != bj) {
    float* Cq = C + (size_t)(rowB0 + wc * 64) * SIZE + rowA0 + wr * 64;
#pragma unroll
    for (int n = 0; n < 4; ++n)
#pragma unroll
      for (int m = 0; m < 4; ++m)
        *reinterpret_cast<f32x4*>(
            &Cq[(size_t)(n * 16 + r16) * SIZE + m * 16 + kg * 4]) = acc[m][n];
  }
}

// ---------------------------------------------------------------------------
extern "C" void kernel_launch(void* const* d_in, const int* in_sizes, int n_in,
                              void* d_out, int out_size, void* d_ws, size_t ws_size,
                              hipStream_t stream) {
  const float* p = (const float*)d_in[0];
  float* C = (float*)d_out;
  __bf16* Lb = (__bf16*)d_ws;  // 4096*4096*2 = 32 MB scratch

  build_L<<<SIZE, 256, 0, stream>>>(p, Lb);
  syrk_bf16<<<NTRI, 256, 0, stream>>>(Lb, C);
}